// Round 11
// baseline (159.678 us; speedup 1.0000x reference)
//
#include <hip/hip_runtime.h>

// DOFEN inference fused pipeline — fp32 I/O, MFMA core.
// Shapes: B=1024, NCOL=NCOND=64, NRODT=1024, D=4, NEST=128, NFOREST=100,
//         NHID=128, NCLASS=10.
//
// Round 18: pstat-LN retry with the register budget done right.
// r17 spilled because (256,4) caps VGPR at 128 < the ~132 live peak
// (WRITE_SIZE 6.4->27 MB = scratch).  This round: identical pstat forest
// but __launch_bounds__(256,3) (cap ~170, the bound r16 ran spill-free
// with MORE live state).  LDS 51.2->19.5 KB (zC deleted), 5 barriers
// (was 6), ~128 fewer LDS f32 ops/thread; occupancy still 12 waves/CU
// (VGPR-bound 3 waves/SIMD instead of LDS-bound 3 blocks/CU).
// All prefetches pinned before barriers (pe->B1, pw->B2, pl2->B4).
// Tripwires: VGPR must read >128 (pins held), WRITE_SIZE ~6.4 MB (no
// spill).  If either fails, revert to r16 (138.9 best).
// History: r13 N-split win; r14 prefetch win; r15 unpinned regression;
// r16 consolidation best 138.9; r17 cap-128 spill regression.

#define B_      1024
#define NCOL_   64
#define NCOND_  64
#define NRODT_  1024
#define NEST_   128
#define NFOREST_ 100
#define NHID_   128
#define NCLASS_ 10
#define EPS_    1e-5f

typedef __bf16 bf16_t;
typedef bf16_t bf16x8 __attribute__((ext_vector_type(8)));
typedef float  f32x4  __attribute__((ext_vector_type(4)));

#define MFMA16(a,b,c) __builtin_amdgcn_mfma_f32_16x16x32_bf16(a,b,c,0,0,0)

#define EG_FRAGS   (NFOREST_*4*8*64)   // 204800 frag-rows of 8 bf16
#define W1_FRAGS   (4*8*64)            // 2048
#define L2_FRAGS   (4*64)              // 256

#define ZLD 136                        // bf16 panel row pad: 272B, 16B-aligned

// ---------------------------------------------------------------------------
// k_prep: B-fragment tables (Esel/f, lin1w, lin2w hi/lo) + x_t + out init.
// blocks: [0,800) Esel  [800,808) lin1w  [808] lin2w  [809,1065) x_t
//         [1065,1105) out = lin2b broadcast.   grid = 1105 x 256.
// ---------------------------------------------------------------------------
__global__ __launch_bounds__(256) void k_prep(
    const float* __restrict__ E,     const int*   __restrict__ swr,
    const float* __restrict__ lin1w, const float* __restrict__ lin2w,
    const float* __restrict__ x,     const float* __restrict__ lin2b,
    bf16_t* __restrict__ Eh,  bf16_t* __restrict__ El,
    bf16_t* __restrict__ Wh,  bf16_t* __restrict__ Wl,
    bf16_t* __restrict__ L2h, bf16_t* __restrict__ L2l,
    float*  __restrict__ x_t, float* __restrict__ out)
{
    int blk = blockIdx.x, tid = threadIdx.x;
    if (blk < 800) {                              // Esel frags: t=(((f*4+kk)*8+nn)*64+lane)
        int t = blk * 256 + tid;
        int lane = t & 63, nn = (t >> 6) & 7, kk = (t >> 9) & 3, f = t >> 11;
        int q = lane >> 4, n = nn * 16 + (lane & 15);
        bf16x8 hi, lo;
#pragma unroll
        for (int j = 0; j < 8; ++j) {
            int e = kk * 32 + q * 8 + j;
            int r = swr[f * NEST_ + e];
            float v = E[r * NHID_ + n];
            bf16_t h = (bf16_t)v;
            hi[j] = h; lo[j] = (bf16_t)(v - (float)h);
        }
        *(bf16x8*)(Eh + (size_t)t * 8) = hi;
        *(bf16x8*)(El + (size_t)t * 8) = lo;
    } else if (blk < 808) {                       // lin1w frags: t=(kk*8+nn)*64+lane
        int t = (blk - 800) * 256 + tid;
        int lane = t & 63, nn = (t >> 6) & 7, kk = t >> 9;
        int q = lane >> 4, n = nn * 16 + (lane & 15);
        bf16x8 hi, lo;
#pragma unroll
        for (int j = 0; j < 8; ++j) {
            int k = kk * 32 + q * 8 + j;
            float v = lin1w[k * NHID_ + n];
            bf16_t h = (bf16_t)v;
            hi[j] = h; lo[j] = (bf16_t)(v - (float)h);
        }
        *(bf16x8*)(Wh + t * 8) = hi;
        *(bf16x8*)(Wl + t * 8) = lo;
    } else if (blk == 808) {                      // lin2w frags (N pad 16): t=kk*64+lane
        int t = tid;
        int lane = t & 63, kk = t >> 6;
        int q = lane >> 4, n = lane & 15;
        bf16x8 hi, lo;
#pragma unroll
        for (int j = 0; j < 8; ++j) {
            int k = kk * 32 + q * 8 + j;
            float v = (n < NCLASS_) ? lin2w[k * NCLASS_ + n] : 0.f;
            bf16_t h = (bf16_t)v;
            hi[j] = h; lo[j] = (bf16_t)(v - (float)h);
        }
        *(bf16x8*)(L2h + t * 8) = hi;
        *(bf16x8*)(L2l + t * 8) = lo;
    } else if (blk < 1065) {                      // x_t[col][b] = x[b][col]
        int t = (blk - 809) * 256 + tid;
        x_t[t] = x[(t & 1023) * NCOL_ + (t >> 10)];
    } else {                                      // out init = lin2_b broadcast
        int t = (blk - 1065) * 256 + tid;
        if (t < B_ * NCLASS_) out[t] = lin2b[t % NCLASS_];
    }
}

// ---------------------------------------------------------------------------
// k_rodt: one g per block (params scalar-uniform); thread handles 4 b's.
// ---------------------------------------------------------------------------
__global__ __launch_bounds__(256) void k_rodt(
    const float* __restrict__ x_t,  const float* __restrict__ w1,
    const float* __restrict__ b1,   const int*  __restrict__ perm,
    const float* __restrict__ gn1g, const float* __restrict__ gn1b,
    const float* __restrict__ w2a,  const float* __restrict__ b2a,
    const float* __restrict__ gn2g, const float* __restrict__ gn2b,
    const float* __restrict__ w2b,  const float* __restrict__ b2b,
    float* __restrict__ w_t)
{
    int g  = blockIdx.x;
    int bq = threadIdx.x * 4;

    int4 p4 = ((const int4*)perm)[g];
    int col[4]  = { p4.x & 63, p4.y & 63, p4.z & 63, p4.w & 63 };
    int cond[4] = { p4.x >> 6, p4.y >> 6, p4.z >> 6, p4.w >> 6 };
    float w1v[4], b1v[4];
#pragma unroll
    for (int j = 0; j < 4; ++j) {
        w1v[j] = w1[col[j] * NCOND_ + cond[j]];
        b1v[j] = b1[col[j] * NCOND_ + cond[j]];
    }
    float4 g1  = ((const float4*)gn1g)[g];
    float4 o1  = ((const float4*)gn1b)[g];
    float4 ba  = ((const float4*)b2a)[g];
    float4 g2  = ((const float4*)gn2g)[g];
    float4 o2  = ((const float4*)gn2b)[g];
    float4 wb4 = ((const float4*)w2b)[g];
    float  bb  = b2b[g];
    float4 wa[4];
    const float4* w2a4 = (const float4*)w2a;
#pragma unroll
    for (int i = 0; i < 4; ++i) wa[i] = w2a4[g * 4 + i];

    float xv[4][4];
#pragma unroll
    for (int j = 0; j < 4; ++j) {
        float4 t = *(const float4*)&x_t[col[j] * B_ + bq];
        xv[j][0] = t.x; xv[j][1] = t.y; xv[j][2] = t.z; xv[j][3] = t.w;
    }

    float outv[4];
#pragma unroll
    for (int bi = 0; bi < 4; ++bi) {
        float v[4];
#pragma unroll
        for (int j = 0; j < 4; ++j) {
            float t = xv[j][bi] * w1v[j] + b1v[j];
            v[j] = 1.0f / (1.0f + __expf(-t));
        }
        float mu = (v[0] + v[1] + v[2] + v[3]) * 0.25f;
        float var = 0.f;
#pragma unroll
        for (int j = 0; j < 4; ++j) { float d = v[j] - mu; var += d * d; }
        var *= 0.25f;
        float rs = rsqrtf(var + EPS_);
        float h[4];
        h[0] = (v[0] - mu) * rs * g1.x + o1.x;
        h[1] = (v[1] - mu) * rs * g1.y + o1.y;
        h[2] = (v[2] - mu) * rs * g1.z + o1.z;
        h[3] = (v[3] - mu) * rs * g1.w + o1.w;

        float4 a = ba;
#pragma unroll
        for (int i = 0; i < 4; ++i) {
            a.x += h[i] * wa[i].x; a.y += h[i] * wa[i].y;
            a.z += h[i] * wa[i].z; a.w += h[i] * wa[i].w;
        }
        float t2[4];
        t2[0] = fmaxf(a.x, 0.f); t2[1] = fmaxf(a.y, 0.f);
        t2[2] = fmaxf(a.z, 0.f); t2[3] = fmaxf(a.w, 0.f);

        float mu2 = (t2[0] + t2[1] + t2[2] + t2[3]) * 0.25f;
        float var2 = 0.f;
#pragma unroll
        for (int j = 0; j < 4; ++j) { float d = t2[j] - mu2; var2 += d * d; }
        var2 *= 0.25f;
        float rs2 = rsqrtf(var2 + EPS_);

        float wvv = bb;
        wvv += ((t2[0] - mu2) * rs2 * g2.x + o2.x) * wb4.x;
        wvv += ((t2[1] - mu2) * rs2 * g2.y + o2.y) * wb4.y;
        wvv += ((t2[2] - mu2) * rs2 * g2.z + o2.z) * wb4.z;
        wvv += ((t2[3] - mu2) * rs2 * g2.w + o2.w) * wb4.w;
        outv[bi] = wvv;
    }
    *(float4*)&w_t[(size_t)g * B_ + bq] = make_float4(outv[0], outv[1], outv[2], outv[3]);
}

// ---------------------------------------------------------------------------
// k_forest: block = (f, 64 rows), 4 waves.  N-split GEMMs; LN via partial
// (sum,sumsq) exchange (pstat, bit-safe per r15/r17) — no f32 C exchange.
// ALL prefetches pinned before barriers (pe->B1, pw->B2, pl2->B4).
// Wave computes ALL 64 rows x n-tiles {2wid,2wid+1}; normalizes its own
// accumulator slice in registers.  zb (bf16 [64][ZLD]) carries ws->z1->z2.
// launch_bounds(256,3): cap ~170 > ~132 live peak (r17's cap-128 spilled).
// lane: q=lane>>4, mc=lane&15.  A row m=(mt*16+)mc, k=kk*32+q*8+j.
// C: row=(mt*16+)q*4+reg, col=nn*16+mc.  atomicAdd accO/NFOREST -> d_out.
// ---------------------------------------------------------------------------
__global__ __launch_bounds__(256, 3) void k_forest(
    const float*  __restrict__ w_t, const int* __restrict__ swr,
    const bf16_t* __restrict__ Eh,  const bf16_t* __restrict__ El,
    const bf16_t* __restrict__ Wh,  const bf16_t* __restrict__ Wl,
    const bf16_t* __restrict__ L2h, const bf16_t* __restrict__ L2l,
    const float* __restrict__ ln1g, const float* __restrict__ ln1b,
    const float* __restrict__ lin1b,
    const float* __restrict__ ln2g, const float* __restrict__ ln2b,
    float* __restrict__ out)
{
    __shared__ __align__(16) bf16_t zb[64 * ZLD];    // 17408 B
    __shared__ __align__(8)  float2 pstat[4][64];    //  2048 B

    int tid  = threadIdx.x;
    int wid  = tid >> 6;
    int lane = tid & 63;
    int q    = lane >> 4;
    int mc   = lane & 15;

    int n    = blockIdx.x;
    int swiz = (n & 7) * 200 + (n >> 3);  // co-locate same-f blocks per XCD
    int f    = swiz >> 4;
    int bt   = swiz & 15;
    int b0   = bt * 64 + wid * 16;        // this wave's softmax/output rows

    const int* swrf = swr + f * NEST_;
    int nn0 = wid * 2;                    // this wave's n-tiles

    const bf16x8* EHf = (const bf16x8*)Eh;
    const bf16x8* ELf = (const bf16x8*)El;
    const bf16x8* WHf = (const bf16x8*)Wh;
    const bf16x8* WLf = (const bf16x8*)Wl;
    const bf16x8* LHf = (const bf16x8*)L2h;
    const bf16x8* LLf = (const bf16x8*)L2l;

    // ---- P0: softmax rows [b0,b0+16): ws[m=mc][e=kk*32+q*8+j] ----
    float ex[4][8];
    float mx = -1e30f;
#pragma unroll
    for (int kk = 0; kk < 4; ++kk) {
        int4 r0 = *(const int4*)(swrf + kk * 32 + q * 8);
        int4 r1 = *(const int4*)(swrf + kk * 32 + q * 8 + 4);
        int rr[8] = { r0.x, r0.y, r0.z, r0.w, r1.x, r1.y, r1.z, r1.w };
#pragma unroll
        for (int j = 0; j < 8; ++j) {
            float v = w_t[rr[j] * B_ + b0 + mc];
            ex[kk][j] = v;
            mx = fmaxf(mx, v);
        }
    }

    // PREFETCH all E-frags (pinned: issued before B1, drained there while
    // the exp/shuffle work below runs).
    bf16x8 pe[4][4];
#pragma unroll
    for (int kk = 0; kk < 4; ++kk) {
        size_t bi = (size_t)(f * 4 + kk) * 8;
        pe[kk][0] = EHf[(bi + nn0) * 64 + lane];
        pe[kk][1] = EHf[(bi + nn0 + 1) * 64 + lane];
        pe[kk][2] = ELf[(bi + nn0) * 64 + lane];
        pe[kk][3] = ELf[(bi + nn0 + 1) * 64 + lane];
    }

    mx = fmaxf(mx, __shfl_xor(mx, 16));
    mx = fmaxf(mx, __shfl_xor(mx, 32));
    float s = 0.f;
#pragma unroll
    for (int kk = 0; kk < 4; ++kk)
#pragma unroll
        for (int j = 0; j < 8; ++j) { ex[kk][j] = __expf(ex[kk][j] - mx); s += ex[kk][j]; }
    s += __shfl_xor(s, 16);
    s += __shfl_xor(s, 32);
    float inv = 1.f / s;

    // write ws into A-panel: row = wid*16+mc, k = kk*32+q*8+j
#pragma unroll
    for (int kk = 0; kk < 4; ++kk) {
        bf16x8 v;
#pragma unroll
        for (int j = 0; j < 8; ++j) v[j] = (bf16_t)(ex[kk][j] * inv);
        *(bf16x8*)&zb[(wid * 16 + mc) * ZLD + kk * 32 + q * 8] = v;
    }

    __syncthreads();   // B1: ws complete (drains E prefetch)

    // ---- P1: F-GEMM, all 64 rows x 2 n-tiles, B from prefetched regs ----
    f32x4 accF[4][2];
#pragma unroll
    for (int mt = 0; mt < 4; ++mt) {
        accF[mt][0] = (f32x4){0.f, 0.f, 0.f, 0.f};
        accF[mt][1] = (f32x4){0.f, 0.f, 0.f, 0.f};
    }
#pragma unroll
    for (int kk = 0; kk < 4; ++kk) {
        bf16x8 av[4];
#pragma unroll
        for (int mt = 0; mt < 4; ++mt)
            av[mt] = *(const bf16x8*)&zb[(mt * 16 + mc) * ZLD + kk * 32 + q * 8];
#pragma unroll
        for (int mt = 0; mt < 4; ++mt) {
            accF[mt][0] = MFMA16(av[mt], pe[kk][0], accF[mt][0]);
            accF[mt][1] = MFMA16(av[mt], pe[kk][1], accF[mt][1]);
            accF[mt][0] = MFMA16(av[mt], pe[kk][2], accF[mt][0]);
            accF[mt][1] = MFMA16(av[mt], pe[kk][3], accF[mt][1]);
        }
    }

    // per-row partials over this wave's 32 cols -> pstat[wid]
#pragma unroll
    for (int mt = 0; mt < 4; ++mt)
#pragma unroll
        for (int reg = 0; reg < 4; ++reg) {
            float a0 = accF[mt][0][reg], a1 = accF[mt][1][reg];
            float sp = a0 + a1;
            float qp = a0 * a0 + a1 * a1;
#pragma unroll
            for (int o = 1; o <= 8; o <<= 1) { sp += __shfl_xor(sp, o); qp += __shfl_xor(qp, o); }
            if (mc == 0) pstat[wid][mt * 16 + q * 4 + reg] = make_float2(sp, qp);
        }

    // PREFETCH all W-frags (pinned: before B2; LN1 below covers latency).
    bf16x8 pw[4][4];
#pragma unroll
    for (int kk = 0; kk < 4; ++kk) {
        pw[kk][0] = WHf[(kk * 8 + nn0) * 64 + lane];
        pw[kk][1] = WHf[(kk * 8 + nn0 + 1) * 64 + lane];
        pw[kk][2] = WLf[(kk * 8 + nn0) * 64 + lane];
        pw[kk][3] = WLf[(kk * 8 + nn0 + 1) * 64 + lane];
    }

    __syncthreads();   // B2: pstat ready (drains W prefetch)

    // ---- P2: LN1 inline — combine partials, normalize own slice -> z1 ----
    {
        float gv0 = ln1g[nn0 * 16 + mc],      bv0 = ln1b[nn0 * 16 + mc];
        float gv1 = ln1g[nn0 * 16 + 16 + mc], bv1 = ln1b[nn0 * 16 + 16 + mc];
#pragma unroll
        for (int mt = 0; mt < 4; ++mt)
#pragma unroll
            for (int reg = 0; reg < 4; ++reg) {
                int r = mt * 16 + q * 4 + reg;
                float2 p0 = pstat[0][r], p1 = pstat[1][r];
                float2 p2 = pstat[2][r], p3 = pstat[3][r];
                float sv = (p0.x + p1.x) + (p2.x + p3.x);
                float qv = (p0.y + p1.y) + (p2.y + p3.y);
                float m_ = sv * (1.f / NHID_);
                float rv = rsqrtf(qv * (1.f / NHID_) - m_ * m_ + EPS_);
                zb[r * ZLD + nn0 * 16 + mc] =
                    (bf16_t)((accF[mt][0][reg] - m_) * rv * gv0 + bv0);
                zb[r * ZLD + nn0 * 16 + 16 + mc] =
                    (bf16_t)((accF[mt][1][reg] - m_) * rv * gv1 + bv1);
            }
    }

    __syncthreads();   // B3: z1 complete

    // ---- P3: lin1 GEMM, all 64 rows x 2 n-tiles, B from prefetched regs ----
    f32x4 accA[4][2];
#pragma unroll
    for (int mt = 0; mt < 4; ++mt) {
        accA[mt][0] = (f32x4){0.f, 0.f, 0.f, 0.f};
        accA[mt][1] = (f32x4){0.f, 0.f, 0.f, 0.f};
    }
#pragma unroll
    for (int kk = 0; kk < 4; ++kk) {
        bf16x8 av[4];
#pragma unroll
        for (int mt = 0; mt < 4; ++mt)
            av[mt] = *(const bf16x8*)&zb[(mt * 16 + mc) * ZLD + kk * 32 + q * 8];
#pragma unroll
        for (int mt = 0; mt < 4; ++mt) {
            accA[mt][0] = MFMA16(av[mt], pw[kk][0], accA[mt][0]);
            accA[mt][1] = MFMA16(av[mt], pw[kk][1], accA[mt][1]);
            accA[mt][0] = MFMA16(av[mt], pw[kk][2], accA[mt][0]);
            accA[mt][1] = MFMA16(av[mt], pw[kk][3], accA[mt][1]);
        }
    }

    // bias + ReLU in place, then per-row partials -> pstat[wid]
    {
        float bb0 = lin1b[nn0 * 16 + mc];
        float bb1 = lin1b[nn0 * 16 + 16 + mc];
#pragma unroll
        for (int mt = 0; mt < 4; ++mt)
#pragma unroll
            for (int reg = 0; reg < 4; ++reg) {
                accA[mt][0][reg] = fmaxf(accA[mt][0][reg] + bb0, 0.f);
                accA[mt][1][reg] = fmaxf(accA[mt][1][reg] + bb1, 0.f);
            }
    }
#pragma unroll
    for (int mt = 0; mt < 4; ++mt)
#pragma unroll
        for (int reg = 0; reg < 4; ++reg) {
            float a0 = accA[mt][0][reg], a1 = accA[mt][1][reg];
            float sp = a0 + a1;
            float qp = a0 * a0 + a1 * a1;
#pragma unroll
            for (int o = 1; o <= 8; o <<= 1) { sp += __shfl_xor(sp, o); qp += __shfl_xor(qp, o); }
            if (mc == 0) pstat[wid][mt * 16 + q * 4 + reg] = make_float2(sp, qp);
        }

    // PREFETCH lin2 frags (pinned: before B4).
    bf16x8 pl2[4][2];
#pragma unroll
    for (int kk = 0; kk < 4; ++kk) {
        pl2[kk][0] = LHf[kk * 64 + lane];
        pl2[kk][1] = LLf[kk * 64 + lane];
    }

    __syncthreads();   // B4: pstat (LN2) ready (drains lin2 prefetch)

    // ---- P4: LN2 inline — normalize own slice -> z2 ----
    {
        float gv0 = ln2g[nn0 * 16 + mc],      bv0 = ln2b[nn0 * 16 + mc];
        float gv1 = ln2g[nn0 * 16 + 16 + mc], bv1 = ln2b[nn0 * 16 + 16 + mc];
#pragma unroll
        for (int mt = 0; mt < 4; ++mt)
#pragma unroll
            for (int reg = 0; reg < 4; ++reg) {
                int r = mt * 16 + q * 4 + reg;
                float2 p0 = pstat[0][r], p1 = pstat[1][r];
                float2 p2 = pstat[2][r], p3 = pstat[3][r];
                float sv = (p0.x + p1.x) + (p2.x + p3.x);
                float qv = (p0.y + p1.y) + (p2.y + p3.y);
                float m_ = sv * (1.f / NHID_);
                float rv = rsqrtf(qv * (1.f / NHID_) - m_ * m_ + EPS_);
                zb[r * ZLD + nn0 * 16 + mc] =
                    (bf16_t)((accA[mt][0][reg] - m_) * rv * gv0 + bv0);
                zb[r * ZLD + nn0 * 16 + 16 + mc] =
                    (bf16_t)((accA[mt][1][reg] - m_) * rv * gv1 + bv1);
            }
    }

    __syncthreads();   // B5: z2 complete

    // ---- P5: lin2 own 16 rows, full K; atomicAdd (scaled) into d_out ----
    f32x4 accO = {0.f, 0.f, 0.f, 0.f};
#pragma unroll
    for (int kk = 0; kk < 4; ++kk) {
        bf16x8 a3 = *(const bf16x8*)&zb[(wid * 16 + mc) * ZLD + kk * 32 + q * 8];
        accO = MFMA16(a3, pl2[kk][0], accO);
        accO = MFMA16(a3, pl2[kk][1], accO);
    }
    if (mc < NCLASS_) {
#pragma unroll
        for (int reg = 0; reg < 4; ++reg)
            atomicAdd(&out[(b0 + q * 4 + reg) * NCLASS_ + mc],
                      accO[reg] * (1.f / NFOREST_));
    }
}

// ---------------------------------------------------------------------------
extern "C" void kernel_launch(void* const* d_in, const int* in_sizes, int n_in,
                              void* d_out, int out_size, void* d_ws, size_t ws_size,
                              hipStream_t stream)
{
    const float* x     = (const float*)d_in[0];
    const float* w1    = (const float*)d_in[1];
    const float* b1    = (const float*)d_in[2];
    const int*   perm  = (const int*)  d_in[3];
    const float* gn1g  = (const float*)d_in[4];
    const float* gn1b  = (const float*)d_in[5];
    const float* w2a   = (const float*)d_in[6];
    const float* b2a   = (const float*)d_in[7];
    const float* gn2g  = (const float*)d_in[8];
    const float* gn2b  = (const float*)d_in[9];
    const float* w2b   = (const float*)d_in[10];
    const float* b2b   = (const float*)d_in[11];
    const float* E     = (const float*)d_in[12];
    const int*   swr   = (const int*)  d_in[13];
    const float* ln1g  = (const float*)d_in[14];
    const float* ln1b  = (const float*)d_in[15];
    const float* lin1w = (const float*)d_in[16];
    const float* lin1b = (const float*)d_in[17];
    const float* ln2g  = (const float*)d_in[18];
    const float* ln2b  = (const float*)d_in[19];
    const float* lin2w = (const float*)d_in[20];
    const float* lin2b = (const float*)d_in[21];

    char* base = (char*)d_ws;
    float*  w_t  = (float*)base;                                    // 4 MB
    float*  x_t  = (float*)(base + 4u * 1024 * 1024 + 64 * 1024);   // 256 KB
    bf16_t* Eh   = (bf16_t*)(base + 4u * 1024 * 1024 + 64 * 1024 + 256 * 1024);
    bf16_t* El   = Eh  + (size_t)EG_FRAGS * 8;
    bf16_t* Wh   = El  + (size_t)EG_FRAGS * 8;
    bf16_t* Wl   = Wh  + (size_t)W1_FRAGS * 8;
    bf16_t* L2h  = Wl  + (size_t)W1_FRAGS * 8;
    bf16_t* L2l  = L2h + (size_t)L2_FRAGS * 8;

    k_prep<<<1105, 256, 0, stream>>>(E, swr, lin1w, lin2w, x, lin2b,
                                     Eh, El, Wh, Wl, L2h, L2l, x_t,
                                     (float*)d_out);

    k_rodt<<<NRODT_, 256, 0, stream>>>(
        x_t, w1, b1, perm, gn1g, gn1b, w2a, b2a, gn2g, gn2b, w2b, b2b, w_t);

    k_forest<<<NFOREST_ * 16, 256, 0, stream>>>(
        w_t, swr, Eh, El, Wh, Wl, L2h, L2l,
        ln1g, ln1b, lin1b, ln2g, ln2b, (float*)d_out);
}

// Round 12
// 138.106 us; speedup vs baseline: 1.1562x; 1.1562x over previous
//
#include <hip/hip_runtime.h>

// DOFEN inference fused pipeline — fp32 I/O, MFMA core.
// Shapes: B=1024, NCOL=NCOND=64, NRODT=1024, D=4, NEST=128, NFOREST=100,
//         NHID=128, NCLASS=10.
//
// Round 19: REVERT to round-16 exactly (138.9 us, session best).
// The pstat/in-register-LN branch is dead: r15 (unpinned), r17 (cap-128
// spill), r18 (cap-170, VGPR readback 72) all show the compiler sinks the
// B-frag prefetch loads when LN consumes accumulators in registers —
// barrier-pinning holds only when the prefetched regs are the sole live
// producers across the barrier (the zC structure).  r16 = N-split GEMMs
// (B-frags once/block) + full cross-barrier prefetch (pe->B1, pw->B3,
// pl2->B4) + zC f32 C-exchange LN + k_final folded into forest atomics.
// History: r13 N-split win; r14 prefetch win; r15/r17/r18 pstat
// regressions; r16 consolidation best (138.9).

#define B_      1024
#define NCOL_   64
#define NCOND_  64
#define NRODT_  1024
#define NEST_   128
#define NFOREST_ 100
#define NHID_   128
#define NCLASS_ 10
#define EPS_    1e-5f

typedef __bf16 bf16_t;
typedef bf16_t bf16x8 __attribute__((ext_vector_type(8)));
typedef float  f32x4  __attribute__((ext_vector_type(4)));

#define MFMA16(a,b,c) __builtin_amdgcn_mfma_f32_16x16x32_bf16(a,b,c,0,0,0)

#define EG_FRAGS   (NFOREST_*4*8*64)   // 204800 frag-rows of 8 bf16
#define W1_FRAGS   (4*8*64)            // 2048
#define L2_FRAGS   (4*64)              // 256

#define ZLD 136                        // bf16 panel row pad: 272B, 16B-aligned

// ---------------------------------------------------------------------------
// k_prep: B-fragment tables (Esel/f, lin1w, lin2w hi/lo) + x_t + out init.
// blocks: [0,800) Esel  [800,808) lin1w  [808] lin2w  [809,1065) x_t
//         [1065,1105) out = lin2b broadcast.   grid = 1105 x 256.
// ---------------------------------------------------------------------------
__global__ __launch_bounds__(256) void k_prep(
    const float* __restrict__ E,     const int*   __restrict__ swr,
    const float* __restrict__ lin1w, const float* __restrict__ lin2w,
    const float* __restrict__ x,     const float* __restrict__ lin2b,
    bf16_t* __restrict__ Eh,  bf16_t* __restrict__ El,
    bf16_t* __restrict__ Wh,  bf16_t* __restrict__ Wl,
    bf16_t* __restrict__ L2h, bf16_t* __restrict__ L2l,
    float*  __restrict__ x_t, float* __restrict__ out)
{
    int blk = blockIdx.x, tid = threadIdx.x;
    if (blk < 800) {                              // Esel frags: t=(((f*4+kk)*8+nn)*64+lane)
        int t = blk * 256 + tid;
        int lane = t & 63, nn = (t >> 6) & 7, kk = (t >> 9) & 3, f = t >> 11;
        int q = lane >> 4, n = nn * 16 + (lane & 15);
        bf16x8 hi, lo;
#pragma unroll
        for (int j = 0; j < 8; ++j) {
            int e = kk * 32 + q * 8 + j;
            int r = swr[f * NEST_ + e];
            float v = E[r * NHID_ + n];
            bf16_t h = (bf16_t)v;
            hi[j] = h; lo[j] = (bf16_t)(v - (float)h);
        }
        *(bf16x8*)(Eh + (size_t)t * 8) = hi;
        *(bf16x8*)(El + (size_t)t * 8) = lo;
    } else if (blk < 808) {                       // lin1w frags: t=(kk*8+nn)*64+lane
        int t = (blk - 800) * 256 + tid;
        int lane = t & 63, nn = (t >> 6) & 7, kk = t >> 9;
        int q = lane >> 4, n = nn * 16 + (lane & 15);
        bf16x8 hi, lo;
#pragma unroll
        for (int j = 0; j < 8; ++j) {
            int k = kk * 32 + q * 8 + j;
            float v = lin1w[k * NHID_ + n];
            bf16_t h = (bf16_t)v;
            hi[j] = h; lo[j] = (bf16_t)(v - (float)h);
        }
        *(bf16x8*)(Wh + t * 8) = hi;
        *(bf16x8*)(Wl + t * 8) = lo;
    } else if (blk == 808) {                      // lin2w frags (N pad 16): t=kk*64+lane
        int t = tid;
        int lane = t & 63, kk = t >> 6;
        int q = lane >> 4, n = lane & 15;
        bf16x8 hi, lo;
#pragma unroll
        for (int j = 0; j < 8; ++j) {
            int k = kk * 32 + q * 8 + j;
            float v = (n < NCLASS_) ? lin2w[k * NCLASS_ + n] : 0.f;
            bf16_t h = (bf16_t)v;
            hi[j] = h; lo[j] = (bf16_t)(v - (float)h);
        }
        *(bf16x8*)(L2h + t * 8) = hi;
        *(bf16x8*)(L2l + t * 8) = lo;
    } else if (blk < 1065) {                      // x_t[col][b] = x[b][col]
        int t = (blk - 809) * 256 + tid;
        x_t[t] = x[(t & 1023) * NCOL_ + (t >> 10)];
    } else {                                      // out init = lin2_b broadcast
        int t = (blk - 1065) * 256 + tid;
        if (t < B_ * NCLASS_) out[t] = lin2b[t % NCLASS_];
    }
}

// ---------------------------------------------------------------------------
// k_rodt: one g per block (params scalar-uniform); thread handles 4 b's.
// ---------------------------------------------------------------------------
__global__ __launch_bounds__(256) void k_rodt(
    const float* __restrict__ x_t,  const float* __restrict__ w1,
    const float* __restrict__ b1,   const int*  __restrict__ perm,
    const float* __restrict__ gn1g, const float* __restrict__ gn1b,
    const float* __restrict__ w2a,  const float* __restrict__ b2a,
    const float* __restrict__ gn2g, const float* __restrict__ gn2b,
    const float* __restrict__ w2b,  const float* __restrict__ b2b,
    float* __restrict__ w_t)
{
    int g  = blockIdx.x;
    int bq = threadIdx.x * 4;

    int4 p4 = ((const int4*)perm)[g];
    int col[4]  = { p4.x & 63, p4.y & 63, p4.z & 63, p4.w & 63 };
    int cond[4] = { p4.x >> 6, p4.y >> 6, p4.z >> 6, p4.w >> 6 };
    float w1v[4], b1v[4];
#pragma unroll
    for (int j = 0; j < 4; ++j) {
        w1v[j] = w1[col[j] * NCOND_ + cond[j]];
        b1v[j] = b1[col[j] * NCOND_ + cond[j]];
    }
    float4 g1  = ((const float4*)gn1g)[g];
    float4 o1  = ((const float4*)gn1b)[g];
    float4 ba  = ((const float4*)b2a)[g];
    float4 g2  = ((const float4*)gn2g)[g];
    float4 o2  = ((const float4*)gn2b)[g];
    float4 wb4 = ((const float4*)w2b)[g];
    float  bb  = b2b[g];
    float4 wa[4];
    const float4* w2a4 = (const float4*)w2a;
#pragma unroll
    for (int i = 0; i < 4; ++i) wa[i] = w2a4[g * 4 + i];

    float xv[4][4];
#pragma unroll
    for (int j = 0; j < 4; ++j) {
        float4 t = *(const float4*)&x_t[col[j] * B_ + bq];
        xv[j][0] = t.x; xv[j][1] = t.y; xv[j][2] = t.z; xv[j][3] = t.w;
    }

    float outv[4];
#pragma unroll
    for (int bi = 0; bi < 4; ++bi) {
        float v[4];
#pragma unroll
        for (int j = 0; j < 4; ++j) {
            float t = xv[j][bi] * w1v[j] + b1v[j];
            v[j] = 1.0f / (1.0f + __expf(-t));
        }
        float mu = (v[0] + v[1] + v[2] + v[3]) * 0.25f;
        float var = 0.f;
#pragma unroll
        for (int j = 0; j < 4; ++j) { float d = v[j] - mu; var += d * d; }
        var *= 0.25f;
        float rs = rsqrtf(var + EPS_);
        float h[4];
        h[0] = (v[0] - mu) * rs * g1.x + o1.x;
        h[1] = (v[1] - mu) * rs * g1.y + o1.y;
        h[2] = (v[2] - mu) * rs * g1.z + o1.z;
        h[3] = (v[3] - mu) * rs * g1.w + o1.w;

        float4 a = ba;
#pragma unroll
        for (int i = 0; i < 4; ++i) {
            a.x += h[i] * wa[i].x; a.y += h[i] * wa[i].y;
            a.z += h[i] * wa[i].z; a.w += h[i] * wa[i].w;
        }
        float t2[4];
        t2[0] = fmaxf(a.x, 0.f); t2[1] = fmaxf(a.y, 0.f);
        t2[2] = fmaxf(a.z, 0.f); t2[3] = fmaxf(a.w, 0.f);

        float mu2 = (t2[0] + t2[1] + t2[2] + t2[3]) * 0.25f;
        float var2 = 0.f;
#pragma unroll
        for (int j = 0; j < 4; ++j) { float d = t2[j] - mu2; var2 += d * d; }
        var2 *= 0.25f;
        float rs2 = rsqrtf(var2 + EPS_);

        float wvv = bb;
        wvv += ((t2[0] - mu2) * rs2 * g2.x + o2.x) * wb4.x;
        wvv += ((t2[1] - mu2) * rs2 * g2.y + o2.y) * wb4.y;
        wvv += ((t2[2] - mu2) * rs2 * g2.z + o2.z) * wb4.z;
        wvv += ((t2[3] - mu2) * rs2 * g2.w + o2.w) * wb4.w;
        outv[bi] = wvv;
    }
    *(float4*)&w_t[(size_t)g * B_ + bq] = make_float4(outv[0], outv[1], outv[2], outv[3]);
}

// ---------------------------------------------------------------------------
// k_forest: block = (f, 64 rows), 4 waves.  N-split GEMMs (r13) + phase
// prefetch pinned before barriers (r14).  Wave computes ALL 64 rows x
// n-tiles {2wid, 2wid+1}; B-frags loaded once per block, prefetched one
// phase early into regs.  A-panel zb (bf16 [64][ZLD]); C-panel zC (f32
// [64][132]).  lane: q=lane>>4, mc=lane&15.  A row m=(mt*16+)mc,
// k=kk*32+q*8+j.  C: row=(mt*16+)q*4+reg, col=nn*16+mc.
// Output: atomicAdd accO/NFOREST into d_out (k_final folded).
// ---------------------------------------------------------------------------
__global__ __launch_bounds__(256, 3) void k_forest(
    const float*  __restrict__ w_t, const int* __restrict__ swr,
    const bf16_t* __restrict__ Eh,  const bf16_t* __restrict__ El,
    const bf16_t* __restrict__ Wh,  const bf16_t* __restrict__ Wl,
    const bf16_t* __restrict__ L2h, const bf16_t* __restrict__ L2l,
    const float* __restrict__ ln1g, const float* __restrict__ ln1b,
    const float* __restrict__ lin1b,
    const float* __restrict__ ln2g, const float* __restrict__ ln2b,
    float* __restrict__ out)
{
    __shared__ __align__(16) float  zC[64 * 132];   // 33792 B: GEMM C exchange
    __shared__ __align__(16) bf16_t zb[64 * ZLD];   // 17408 B: ws -> z1 -> z2

    int tid  = threadIdx.x;
    int wid  = tid >> 6;
    int lane = tid & 63;
    int q    = lane >> 4;
    int mc   = lane & 15;

    int n    = blockIdx.x;
    int swiz = (n & 7) * 200 + (n >> 3);  // co-locate same-f blocks per XCD
    int f    = swiz >> 4;
    int bt   = swiz & 15;
    int b0   = bt * 64 + wid * 16;        // this wave's softmax/output rows

    const int* swrf = swr + f * NEST_;
    int nn0 = wid * 2;                    // this wave's n-tiles

    const bf16x8* EHf = (const bf16x8*)Eh;
    const bf16x8* ELf = (const bf16x8*)El;
    const bf16x8* WHf = (const bf16x8*)Wh;
    const bf16x8* WLf = (const bf16x8*)Wl;
    const bf16x8* LHf = (const bf16x8*)L2h;
    const bf16x8* LLf = (const bf16x8*)L2l;

    // ---- softmax rows [b0,b0+16): ws[m=mc][e=kk*32+q*8+j] ----
    float ex[4][8];
    float mx = -1e30f;
#pragma unroll
    for (int kk = 0; kk < 4; ++kk) {
        int4 r0 = *(const int4*)(swrf + kk * 32 + q * 8);
        int4 r1 = *(const int4*)(swrf + kk * 32 + q * 8 + 4);
        int rr[8] = { r0.x, r0.y, r0.z, r0.w, r1.x, r1.y, r1.z, r1.w };
#pragma unroll
        for (int j = 0; j < 8; ++j) {
            float v = w_t[rr[j] * B_ + b0 + mc];
            ex[kk][j] = v;
            mx = fmaxf(mx, v);
        }
    }

    // PREFETCH E-frags (issued behind the w_t gather; drained at B1 while
    // the exp/shuffle work below runs).  pe[kk] = {h(nn0), h(nn0+1),
    // l(nn0), l(nn0+1)}.
    bf16x8 pe[4][4];
#pragma unroll
    for (int kk = 0; kk < 4; ++kk) {
        size_t bi = (size_t)(f * 4 + kk) * 8;
        pe[kk][0] = EHf[(bi + nn0) * 64 + lane];
        pe[kk][1] = EHf[(bi + nn0 + 1) * 64 + lane];
        pe[kk][2] = ELf[(bi + nn0) * 64 + lane];
        pe[kk][3] = ELf[(bi + nn0 + 1) * 64 + lane];
    }

    mx = fmaxf(mx, __shfl_xor(mx, 16));
    mx = fmaxf(mx, __shfl_xor(mx, 32));
    float s = 0.f;
#pragma unroll
    for (int kk = 0; kk < 4; ++kk)
#pragma unroll
        for (int j = 0; j < 8; ++j) { ex[kk][j] = __expf(ex[kk][j] - mx); s += ex[kk][j]; }
    s += __shfl_xor(s, 16);
    s += __shfl_xor(s, 32);
    float inv = 1.f / s;

    // write ws into A-panel: row = wid*16+mc, k = kk*32+q*8+j
#pragma unroll
    for (int kk = 0; kk < 4; ++kk) {
        bf16x8 v;
#pragma unroll
        for (int j = 0; j < 8; ++j) v[j] = (bf16_t)(ex[kk][j] * inv);
        *(bf16x8*)&zb[(wid * 16 + mc) * ZLD + kk * 32 + q * 8] = v;
    }

    __syncthreads();   // B1: ws complete (also drains E prefetch)

    // ---- F-GEMM: all 64 rows x 2 n-tiles, B from prefetched regs ----
    f32x4 accF[4][2];
#pragma unroll
    for (int mt = 0; mt < 4; ++mt) {
        accF[mt][0] = (f32x4){0.f, 0.f, 0.f, 0.f};
        accF[mt][1] = (f32x4){0.f, 0.f, 0.f, 0.f};
    }
#pragma unroll
    for (int kk = 0; kk < 4; ++kk) {
        bf16x8 av[4];
#pragma unroll
        for (int mt = 0; mt < 4; ++mt)
            av[mt] = *(const bf16x8*)&zb[(mt * 16 + mc) * ZLD + kk * 32 + q * 8];
#pragma unroll
        for (int mt = 0; mt < 4; ++mt) {
            accF[mt][0] = MFMA16(av[mt], pe[kk][0], accF[mt][0]);
            accF[mt][1] = MFMA16(av[mt], pe[kk][1], accF[mt][1]);
            accF[mt][0] = MFMA16(av[mt], pe[kk][2], accF[mt][0]);
            accF[mt][1] = MFMA16(av[mt], pe[kk][3], accF[mt][1]);
        }
    }

    // PREFETCH W-frags (drained at B3; LN1 VALU below covers latency).
    bf16x8 pw[4][4];
#pragma unroll
    for (int kk = 0; kk < 4; ++kk) {
        pw[kk][0] = WHf[(kk * 8 + nn0) * 64 + lane];
        pw[kk][1] = WHf[(kk * 8 + nn0 + 1) * 64 + lane];
        pw[kk][2] = WLf[(kk * 8 + nn0) * 64 + lane];
        pw[kk][3] = WLf[(kk * 8 + nn0 + 1) * 64 + lane];
    }

    // C -> zC: row = mt*16+q*4+reg, col = (nn0+nj)*16+mc
#pragma unroll
    for (int mt = 0; mt < 4; ++mt)
#pragma unroll
        for (int nj = 0; nj < 2; ++nj)
#pragma unroll
            for (int reg = 0; reg < 4; ++reg)
                zC[(mt * 16 + q * 4 + reg) * 132 + (nn0 + nj) * 16 + mc] = accF[mt][nj][reg];

    __syncthreads();   // B2: F complete

    // ---- LayerNorm 1 on own rows (wid*16 + q*4+reg) ----
    {
        float vv[8][4];
#pragma unroll
        for (int nn = 0; nn < 8; ++nn)
#pragma unroll
            for (int reg = 0; reg < 4; ++reg)
                vv[nn][reg] = zC[(wid * 16 + q * 4 + reg) * 132 + nn * 16 + mc];
        float mu[4], rs[4];
#pragma unroll
        for (int reg = 0; reg < 4; ++reg) {
            float ps = 0.f, pq = 0.f;
#pragma unroll
            for (int nn = 0; nn < 8; ++nn) { float v = vv[nn][reg]; ps += v; pq += v * v; }
#pragma unroll
            for (int o = 1; o <= 8; o <<= 1) { ps += __shfl_xor(ps, o); pq += __shfl_xor(pq, o); }
            float m_ = ps * (1.f / NHID_);
            mu[reg] = m_;
            rs[reg] = rsqrtf(pq * (1.f / NHID_) - m_ * m_ + EPS_);
        }
#pragma unroll
        for (int nn = 0; nn < 8; ++nn) {
            int c = nn * 16 + mc;
            float gv = ln1g[c], bv = ln1b[c];
#pragma unroll
            for (int reg = 0; reg < 4; ++reg)
                zb[(wid * 16 + q * 4 + reg) * ZLD + c] =
                    (bf16_t)((vv[nn][reg] - mu[reg]) * rs[reg] * gv + bv);
        }
    }

    __syncthreads();   // B3: z1 complete (also drains W prefetch)

    // ---- lin1 GEMM: all 64 rows x 2 n-tiles, B from prefetched regs ----
    f32x4 accA[4][2];
#pragma unroll
    for (int mt = 0; mt < 4; ++mt) {
        accA[mt][0] = (f32x4){0.f, 0.f, 0.f, 0.f};
        accA[mt][1] = (f32x4){0.f, 0.f, 0.f, 0.f};
    }
#pragma unroll
    for (int kk = 0; kk < 4; ++kk) {
        bf16x8 av[4];
#pragma unroll
        for (int mt = 0; mt < 4; ++mt)
            av[mt] = *(const bf16x8*)&zb[(mt * 16 + mc) * ZLD + kk * 32 + q * 8];
#pragma unroll
        for (int mt = 0; mt < 4; ++mt) {
            accA[mt][0] = MFMA16(av[mt], pw[kk][0], accA[mt][0]);
            accA[mt][1] = MFMA16(av[mt], pw[kk][1], accA[mt][1]);
            accA[mt][0] = MFMA16(av[mt], pw[kk][2], accA[mt][0]);
            accA[mt][1] = MFMA16(av[mt], pw[kk][3], accA[mt][1]);
        }
    }

    __syncthreads();   // B4a: all z1 reads done -> zC reusable
#pragma unroll
    for (int mt = 0; mt < 4; ++mt)
#pragma unroll
        for (int nj = 0; nj < 2; ++nj)
#pragma unroll
            for (int reg = 0; reg < 4; ++reg)
                zC[(mt * 16 + q * 4 + reg) * 132 + (nn0 + nj) * 16 + mc] = accA[mt][nj][reg];

    // PREFETCH lin2 frags (hot in L2, small; drained at B4).
    bf16x8 pl2[4][2];
#pragma unroll
    for (int kk = 0; kk < 4; ++kk) {
        pl2[kk][0] = LHf[kk * 64 + lane];
        pl2[kk][1] = LLf[kk * 64 + lane];
    }

    __syncthreads();   // B4: lin1 C complete

    // ---- bias + ReLU + LayerNorm 2 on own rows; z2 -> zb own rows ----
    {
        float vv[8][4];
#pragma unroll
        for (int nn = 0; nn < 8; ++nn) {
            float bv = lin1b[nn * 16 + mc];
#pragma unroll
            for (int reg = 0; reg < 4; ++reg)
                vv[nn][reg] = fmaxf(
                    zC[(wid * 16 + q * 4 + reg) * 132 + nn * 16 + mc] + bv, 0.f);
        }
        float mu2[4], rs2[4];
#pragma unroll
        for (int reg = 0; reg < 4; ++reg) {
            float ps = 0.f, pq = 0.f;
#pragma unroll
            for (int nn = 0; nn < 8; ++nn) { float v = vv[nn][reg]; ps += v; pq += v * v; }
#pragma unroll
            for (int o = 1; o <= 8; o <<= 1) { ps += __shfl_xor(ps, o); pq += __shfl_xor(pq, o); }
            float m_ = ps * (1.f / NHID_);
            mu2[reg] = m_;
            rs2[reg] = rsqrtf(pq * (1.f / NHID_) - m_ * m_ + EPS_);
        }
#pragma unroll
        for (int nn = 0; nn < 8; ++nn) {
            int c = nn * 16 + mc;
            float gv = ln2g[c], bv = ln2b[c];
#pragma unroll
            for (int reg = 0; reg < 4; ++reg)
                zb[(wid * 16 + q * 4 + reg) * ZLD + c] =
                    (bf16_t)((vv[nn][reg] - mu2[reg]) * rs2[reg] * gv + bv);
        }
    }
    // z2 rows [wid*16, wid*16+16) written & read by this wave only -> no barrier

    // ---- lin2: own 16 rows, 16x128 @ 128x16(padded); atomic into d_out ----
    f32x4 accO = {0.f, 0.f, 0.f, 0.f};
#pragma unroll
    for (int kk = 0; kk < 4; ++kk) {
        bf16x8 a3 = *(const bf16x8*)&zb[(wid * 16 + mc) * ZLD + kk * 32 + q * 8];
        accO = MFMA16(a3, pl2[kk][0], accO);
        accO = MFMA16(a3, pl2[kk][1], accO);
    }
    if (mc < NCLASS_) {
#pragma unroll
        for (int reg = 0; reg < 4; ++reg)
            atomicAdd(&out[(b0 + q * 4 + reg) * NCLASS_ + mc],
                      accO[reg] * (1.f / NFOREST_));
    }
}

// ---------------------------------------------------------------------------
extern "C" void kernel_launch(void* const* d_in, const int* in_sizes, int n_in,
                              void* d_out, int out_size, void* d_ws, size_t ws_size,
                              hipStream_t stream)
{
    const float* x     = (const float*)d_in[0];
    const float* w1    = (const float*)d_in[1];
    const float* b1    = (const float*)d_in[2];
    const int*   perm  = (const int*)  d_in[3];
    const float* gn1g  = (const float*)d_in[4];
    const float* gn1b  = (const float*)d_in[5];
    const float* w2a   = (const float*)d_in[6];
    const float* b2a   = (const float*)d_in[7];
    const float* gn2g  = (const float*)d_in[8];
    const float* gn2b  = (const float*)d_in[9];
    const float* w2b   = (const float*)d_in[10];
    const float* b2b   = (const float*)d_in[11];
    const float* E     = (const float*)d_in[12];
    const int*   swr   = (const int*)  d_in[13];
    const float* ln1g  = (const float*)d_in[14];
    const float* ln1b  = (const float*)d_in[15];
    const float* lin1w = (const float*)d_in[16];
    const float* lin1b = (const float*)d_in[17];
    const float* ln2g  = (const float*)d_in[18];
    const float* ln2b  = (const float*)d_in[19];
    const float* lin2w = (const float*)d_in[20];
    const float* lin2b = (const float*)d_in[21];

    char* base = (char*)d_ws;
    float*  w_t  = (float*)base;                                    // 4 MB
    float*  x_t  = (float*)(base + 4u * 1024 * 1024 + 64 * 1024);   // 256 KB
    bf16_t* Eh   = (bf16_t*)(base + 4u * 1024 * 1024 + 64 * 1024 + 256 * 1024);
    bf16_t* El   = Eh  + (size_t)EG_FRAGS * 8;
    bf16_t* Wh   = El  + (size_t)EG_FRAGS * 8;
    bf16_t* Wl   = Wh  + (size_t)W1_FRAGS * 8;
    bf16_t* L2h  = Wl  + (size_t)W1_FRAGS * 8;
    bf16_t* L2l  = L2h + (size_t)L2_FRAGS * 8;

    k_prep<<<1105, 256, 0, stream>>>(E, swr, lin1w, lin2w, x, lin2b,
                                     Eh, El, Wh, Wl, L2h, L2l, x_t,
                                     (float*)d_out);

    k_rodt<<<NRODT_, 256, 0, stream>>>(
        x_t, w1, b1, perm, gn1g, gn1b, w2a, b2a, gn2g, gn2b, w2b, b2b, w_t);

    k_forest<<<NFOREST_ * 16, 256, 0, stream>>>(
        w_t, swr, Eh, El, Wh, Wl, L2h, L2l,
        ln1g, ln1b, lin1b, ln2g, ln2b, (float*)d_out);
}

// Round 13
// 137.767 us; speedup vs baseline: 1.1590x; 1.0025x over previous
//
#include <hip/hip_runtime.h>

// DOFEN inference fused pipeline — fp32 I/O, MFMA core.
// Shapes: B=1024, NCOL=NCOND=64, NRODT=1024, D=4, NEST=128, NFOREST=100,
//         NHID=128, NCLASS=10.
//
// Round 20: r16/r19 forest (138.1 best, untouched) + prep/rodt launch
// restructure.  Only x_t (256 blocks) is a real dependency for rodt; the
// frag-table gather (809 blocks, latency-bound) and rodt (1024 blocks,
// VALU-bound) are independent with complementary bottlenecks.  New layout:
// k_xt (296 blocks: x_t transpose + out-init, ~2us) then k_main (1833
// blocks: frag tables || rodt co-resident).  All loop bodies byte-identical
// to r19 -> bit-identical output.  Forest = N-split + pinned cross-barrier
// prefetch + zC exchange + folded k_final (proven best; pstat branch dead
// per r15/r17/r18: compiler sinks prefetch when LN consumes accs in regs).

#define B_      1024
#define NCOL_   64
#define NCOND_  64
#define NRODT_  1024
#define NEST_   128
#define NFOREST_ 100
#define NHID_   128
#define NCLASS_ 10
#define EPS_    1e-5f

typedef __bf16 bf16_t;
typedef bf16_t bf16x8 __attribute__((ext_vector_type(8)));
typedef float  f32x4  __attribute__((ext_vector_type(4)));

#define MFMA16(a,b,c) __builtin_amdgcn_mfma_f32_16x16x32_bf16(a,b,c,0,0,0)

#define EG_FRAGS   (NFOREST_*4*8*64)   // 204800 frag-rows of 8 bf16
#define W1_FRAGS   (4*8*64)            // 2048
#define L2_FRAGS   (4*64)              // 256

#define ZLD 136                        // bf16 panel row pad: 272B, 16B-aligned

// ---------------------------------------------------------------------------
// k_xt: x_t transpose + out init.  blocks: [0,256) x_t  [256,296) out.
// ---------------------------------------------------------------------------
__global__ __launch_bounds__(256) void k_xt(
    const float* __restrict__ x, const float* __restrict__ lin2b,
    float* __restrict__ x_t, float* __restrict__ out)
{
    int blk = blockIdx.x, tid = threadIdx.x;
    if (blk < 256) {                              // x_t[col][b] = x[b][col]
        int t = blk * 256 + tid;
        x_t[t] = x[(t & 1023) * NCOL_ + (t >> 10)];
    } else {                                      // out init = lin2_b broadcast
        int t = (blk - 256) * 256 + tid;
        if (t < B_ * NCLASS_) out[t] = lin2b[t % NCLASS_];
    }
}

// ---------------------------------------------------------------------------
// k_main: frag tables || rodt, co-resident.
// blocks: [0,800) Esel  [800,808) lin1w  [808] lin2w  [809,1833) rodt.
// ---------------------------------------------------------------------------
__global__ __launch_bounds__(256) void k_main(
    const float* __restrict__ E,     const int*   __restrict__ swr,
    const float* __restrict__ lin1w, const float* __restrict__ lin2w,
    const float* __restrict__ x_t,   const float* __restrict__ w1,
    const float* __restrict__ b1,    const int*   __restrict__ perm,
    const float* __restrict__ gn1g,  const float* __restrict__ gn1b,
    const float* __restrict__ w2a,   const float* __restrict__ b2a,
    const float* __restrict__ gn2g,  const float* __restrict__ gn2b,
    const float* __restrict__ w2b,   const float* __restrict__ b2b,
    bf16_t* __restrict__ Eh,  bf16_t* __restrict__ El,
    bf16_t* __restrict__ Wh,  bf16_t* __restrict__ Wl,
    bf16_t* __restrict__ L2h, bf16_t* __restrict__ L2l,
    float*  __restrict__ w_t)
{
    int blk = blockIdx.x, tid = threadIdx.x;
    if (blk < 800) {                              // Esel frags: t=(((f*4+kk)*8+nn)*64+lane)
        int t = blk * 256 + tid;
        int lane = t & 63, nn = (t >> 6) & 7, kk = (t >> 9) & 3, f = t >> 11;
        int q = lane >> 4, n = nn * 16 + (lane & 15);
        bf16x8 hi, lo;
#pragma unroll
        for (int j = 0; j < 8; ++j) {
            int e = kk * 32 + q * 8 + j;
            int r = swr[f * NEST_ + e];
            float v = E[r * NHID_ + n];
            bf16_t h = (bf16_t)v;
            hi[j] = h; lo[j] = (bf16_t)(v - (float)h);
        }
        *(bf16x8*)(Eh + (size_t)t * 8) = hi;
        *(bf16x8*)(El + (size_t)t * 8) = lo;
    } else if (blk < 808) {                       // lin1w frags: t=(kk*8+nn)*64+lane
        int t = (blk - 800) * 256 + tid;
        int lane = t & 63, nn = (t >> 6) & 7, kk = t >> 9;
        int q = lane >> 4, n = nn * 16 + (lane & 15);
        bf16x8 hi, lo;
#pragma unroll
        for (int j = 0; j < 8; ++j) {
            int k = kk * 32 + q * 8 + j;
            float v = lin1w[k * NHID_ + n];
            bf16_t h = (bf16_t)v;
            hi[j] = h; lo[j] = (bf16_t)(v - (float)h);
        }
        *(bf16x8*)(Wh + t * 8) = hi;
        *(bf16x8*)(Wl + t * 8) = lo;
    } else if (blk == 808) {                      // lin2w frags (N pad 16): t=kk*64+lane
        int t = tid;
        int lane = t & 63, kk = t >> 6;
        int q = lane >> 4, n = lane & 15;
        bf16x8 hi, lo;
#pragma unroll
        for (int j = 0; j < 8; ++j) {
            int k = kk * 32 + q * 8 + j;
            float v = (n < NCLASS_) ? lin2w[k * NCLASS_ + n] : 0.f;
            bf16_t h = (bf16_t)v;
            hi[j] = h; lo[j] = (bf16_t)(v - (float)h);
        }
        *(bf16x8*)(L2h + t * 8) = hi;
        *(bf16x8*)(L2l + t * 8) = lo;
    } else {                                      // rodt: one g per block
        int g  = blk - 809;
        int bq = tid * 4;

        int4 p4 = ((const int4*)perm)[g];
        int col[4]  = { p4.x & 63, p4.y & 63, p4.z & 63, p4.w & 63 };
        int cond[4] = { p4.x >> 6, p4.y >> 6, p4.z >> 6, p4.w >> 6 };
        float w1v[4], b1v[4];
#pragma unroll
        for (int j = 0; j < 4; ++j) {
            w1v[j] = w1[col[j] * NCOND_ + cond[j]];
            b1v[j] = b1[col[j] * NCOND_ + cond[j]];
        }
        float4 g1  = ((const float4*)gn1g)[g];
        float4 o1  = ((const float4*)gn1b)[g];
        float4 ba  = ((const float4*)b2a)[g];
        float4 g2  = ((const float4*)gn2g)[g];
        float4 o2  = ((const float4*)gn2b)[g];
        float4 wb4 = ((const float4*)w2b)[g];
        float  bb  = b2b[g];
        float4 wa[4];
        const float4* w2a4 = (const float4*)w2a;
#pragma unroll
        for (int i = 0; i < 4; ++i) wa[i] = w2a4[g * 4 + i];

        float xv[4][4];
#pragma unroll
        for (int j = 0; j < 4; ++j) {
            float4 t = *(const float4*)&x_t[col[j] * B_ + bq];
            xv[j][0] = t.x; xv[j][1] = t.y; xv[j][2] = t.z; xv[j][3] = t.w;
        }

        float outv[4];
#pragma unroll
        for (int bi = 0; bi < 4; ++bi) {
            float v[4];
#pragma unroll
            for (int j = 0; j < 4; ++j) {
                float t = xv[j][bi] * w1v[j] + b1v[j];
                v[j] = 1.0f / (1.0f + __expf(-t));
            }
            float mu = (v[0] + v[1] + v[2] + v[3]) * 0.25f;
            float var = 0.f;
#pragma unroll
            for (int j = 0; j < 4; ++j) { float d = v[j] - mu; var += d * d; }
            var *= 0.25f;
            float rs = rsqrtf(var + EPS_);
            float h[4];
            h[0] = (v[0] - mu) * rs * g1.x + o1.x;
            h[1] = (v[1] - mu) * rs * g1.y + o1.y;
            h[2] = (v[2] - mu) * rs * g1.z + o1.z;
            h[3] = (v[3] - mu) * rs * g1.w + o1.w;

            float4 a = ba;
#pragma unroll
            for (int i = 0; i < 4; ++i) {
                a.x += h[i] * wa[i].x; a.y += h[i] * wa[i].y;
                a.z += h[i] * wa[i].z; a.w += h[i] * wa[i].w;
            }
            float t2[4];
            t2[0] = fmaxf(a.x, 0.f); t2[1] = fmaxf(a.y, 0.f);
            t2[2] = fmaxf(a.z, 0.f); t2[3] = fmaxf(a.w, 0.f);

            float mu2 = (t2[0] + t2[1] + t2[2] + t2[3]) * 0.25f;
            float var2 = 0.f;
#pragma unroll
            for (int j = 0; j < 4; ++j) { float d = t2[j] - mu2; var2 += d * d; }
            var2 *= 0.25f;
            float rs2 = rsqrtf(var2 + EPS_);

            float wvv = bb;
            wvv += ((t2[0] - mu2) * rs2 * g2.x + o2.x) * wb4.x;
            wvv += ((t2[1] - mu2) * rs2 * g2.y + o2.y) * wb4.y;
            wvv += ((t2[2] - mu2) * rs2 * g2.z + o2.z) * wb4.z;
            wvv += ((t2[3] - mu2) * rs2 * g2.w + o2.w) * wb4.w;
            outv[bi] = wvv;
        }
        *(float4*)&w_t[(size_t)g * B_ + bq] = make_float4(outv[0], outv[1], outv[2], outv[3]);
    }
}

// ---------------------------------------------------------------------------
// k_forest: block = (f, 64 rows), 4 waves.  N-split GEMMs (r13) + phase
// prefetch pinned before barriers (r14).  Wave computes ALL 64 rows x
// n-tiles {2wid, 2wid+1}; B-frags loaded once per block, prefetched one
// phase early into regs.  A-panel zb (bf16 [64][ZLD]); C-panel zC (f32
// [64][132]).  lane: q=lane>>4, mc=lane&15.  A row m=(mt*16+)mc,
// k=kk*32+q*8+j.  C: row=(mt*16+)q*4+reg, col=nn*16+mc.
// Output: atomicAdd accO/NFOREST into d_out (k_final folded).
// ---------------------------------------------------------------------------
__global__ __launch_bounds__(256, 3) void k_forest(
    const float*  __restrict__ w_t, const int* __restrict__ swr,
    const bf16_t* __restrict__ Eh,  const bf16_t* __restrict__ El,
    const bf16_t* __restrict__ Wh,  const bf16_t* __restrict__ Wl,
    const bf16_t* __restrict__ L2h, const bf16_t* __restrict__ L2l,
    const float* __restrict__ ln1g, const float* __restrict__ ln1b,
    const float* __restrict__ lin1b,
    const float* __restrict__ ln2g, const float* __restrict__ ln2b,
    float* __restrict__ out)
{
    __shared__ __align__(16) float  zC[64 * 132];   // 33792 B: GEMM C exchange
    __shared__ __align__(16) bf16_t zb[64 * ZLD];   // 17408 B: ws -> z1 -> z2

    int tid  = threadIdx.x;
    int wid  = tid >> 6;
    int lane = tid & 63;
    int q    = lane >> 4;
    int mc   = lane & 15;

    int n    = blockIdx.x;
    int swiz = (n & 7) * 200 + (n >> 3);  // co-locate same-f blocks per XCD
    int f    = swiz >> 4;
    int bt   = swiz & 15;
    int b0   = bt * 64 + wid * 16;        // this wave's softmax/output rows

    const int* swrf = swr + f * NEST_;
    int nn0 = wid * 2;                    // this wave's n-tiles

    const bf16x8* EHf = (const bf16x8*)Eh;
    const bf16x8* ELf = (const bf16x8*)El;
    const bf16x8* WHf = (const bf16x8*)Wh;
    const bf16x8* WLf = (const bf16x8*)Wl;
    const bf16x8* LHf = (const bf16x8*)L2h;
    const bf16x8* LLf = (const bf16x8*)L2l;

    // ---- softmax rows [b0,b0+16): ws[m=mc][e=kk*32+q*8+j] ----
    float ex[4][8];
    float mx = -1e30f;
#pragma unroll
    for (int kk = 0; kk < 4; ++kk) {
        int4 r0 = *(const int4*)(swrf + kk * 32 + q * 8);
        int4 r1 = *(const int4*)(swrf + kk * 32 + q * 8 + 4);
        int rr[8] = { r0.x, r0.y, r0.z, r0.w, r1.x, r1.y, r1.z, r1.w };
#pragma unroll
        for (int j = 0; j < 8; ++j) {
            float v = w_t[rr[j] * B_ + b0 + mc];
            ex[kk][j] = v;
            mx = fmaxf(mx, v);
        }
    }

    // PREFETCH E-frags (issued behind the w_t gather; drained at B1 while
    // the exp/shuffle work below runs).  pe[kk] = {h(nn0), h(nn0+1),
    // l(nn0), l(nn0+1)}.
    bf16x8 pe[4][4];
#pragma unroll
    for (int kk = 0; kk < 4; ++kk) {
        size_t bi = (size_t)(f * 4 + kk) * 8;
        pe[kk][0] = EHf[(bi + nn0) * 64 + lane];
        pe[kk][1] = EHf[(bi + nn0 + 1) * 64 + lane];
        pe[kk][2] = ELf[(bi + nn0) * 64 + lane];
        pe[kk][3] = ELf[(bi + nn0 + 1) * 64 + lane];
    }

    mx = fmaxf(mx, __shfl_xor(mx, 16));
    mx = fmaxf(mx, __shfl_xor(mx, 32));
    float s = 0.f;
#pragma unroll
    for (int kk = 0; kk < 4; ++kk)
#pragma unroll
        for (int j = 0; j < 8; ++j) { ex[kk][j] = __expf(ex[kk][j] - mx); s += ex[kk][j]; }
    s += __shfl_xor(s, 16);
    s += __shfl_xor(s, 32);
    float inv = 1.f / s;

    // write ws into A-panel: row = wid*16+mc, k = kk*32+q*8+j
#pragma unroll
    for (int kk = 0; kk < 4; ++kk) {
        bf16x8 v;
#pragma unroll
        for (int j = 0; j < 8; ++j) v[j] = (bf16_t)(ex[kk][j] * inv);
        *(bf16x8*)&zb[(wid * 16 + mc) * ZLD + kk * 32 + q * 8] = v;
    }

    __syncthreads();   // B1: ws complete (also drains E prefetch)

    // ---- F-GEMM: all 64 rows x 2 n-tiles, B from prefetched regs ----
    f32x4 accF[4][2];
#pragma unroll
    for (int mt = 0; mt < 4; ++mt) {
        accF[mt][0] = (f32x4){0.f, 0.f, 0.f, 0.f};
        accF[mt][1] = (f32x4){0.f, 0.f, 0.f, 0.f};
    }
#pragma unroll
    for (int kk = 0; kk < 4; ++kk) {
        bf16x8 av[4];
#pragma unroll
        for (int mt = 0; mt < 4; ++mt)
            av[mt] = *(const bf16x8*)&zb[(mt * 16 + mc) * ZLD + kk * 32 + q * 8];
#pragma unroll
        for (int mt = 0; mt < 4; ++mt) {
            accF[mt][0] = MFMA16(av[mt], pe[kk][0], accF[mt][0]);
            accF[mt][1] = MFMA16(av[mt], pe[kk][1], accF[mt][1]);
            accF[mt][0] = MFMA16(av[mt], pe[kk][2], accF[mt][0]);
            accF[mt][1] = MFMA16(av[mt], pe[kk][3], accF[mt][1]);
        }
    }

    // PREFETCH W-frags (drained at B3; LN1 VALU below covers latency).
    bf16x8 pw[4][4];
#pragma unroll
    for (int kk = 0; kk < 4; ++kk) {
        pw[kk][0] = WHf[(kk * 8 + nn0) * 64 + lane];
        pw[kk][1] = WHf[(kk * 8 + nn0 + 1) * 64 + lane];
        pw[kk][2] = WLf[(kk * 8 + nn0) * 64 + lane];
        pw[kk][3] = WLf[(kk * 8 + nn0 + 1) * 64 + lane];
    }

    // C -> zC: row = mt*16+q*4+reg, col = (nn0+nj)*16+mc
#pragma unroll
    for (int mt = 0; mt < 4; ++mt)
#pragma unroll
        for (int nj = 0; nj < 2; ++nj)
#pragma unroll
            for (int reg = 0; reg < 4; ++reg)
                zC[(mt * 16 + q * 4 + reg) * 132 + (nn0 + nj) * 16 + mc] = accF[mt][nj][reg];

    __syncthreads();   // B2: F complete

    // ---- LayerNorm 1 on own rows (wid*16 + q*4+reg) ----
    {
        float vv[8][4];
#pragma unroll
        for (int nn = 0; nn < 8; ++nn)
#pragma unroll
            for (int reg = 0; reg < 4; ++reg)
                vv[nn][reg] = zC[(wid * 16 + q * 4 + reg) * 132 + nn * 16 + mc];
        float mu[4], rs[4];
#pragma unroll
        for (int reg = 0; reg < 4; ++reg) {
            float ps = 0.f, pq = 0.f;
#pragma unroll
            for (int nn = 0; nn < 8; ++nn) { float v = vv[nn][reg]; ps += v; pq += v * v; }
#pragma unroll
            for (int o = 1; o <= 8; o <<= 1) { ps += __shfl_xor(ps, o); pq += __shfl_xor(pq, o); }
            float m_ = ps * (1.f / NHID_);
            mu[reg] = m_;
            rs[reg] = rsqrtf(pq * (1.f / NHID_) - m_ * m_ + EPS_);
        }
#pragma unroll
        for (int nn = 0; nn < 8; ++nn) {
            int c = nn * 16 + mc;
            float gv = ln1g[c], bv = ln1b[c];
#pragma unroll
            for (int reg = 0; reg < 4; ++reg)
                zb[(wid * 16 + q * 4 + reg) * ZLD + c] =
                    (bf16_t)((vv[nn][reg] - mu[reg]) * rs[reg] * gv + bv);
        }
    }

    __syncthreads();   // B3: z1 complete (also drains W prefetch)

    // ---- lin1 GEMM: all 64 rows x 2 n-tiles, B from prefetched regs ----
    f32x4 accA[4][2];
#pragma unroll
    for (int mt = 0; mt < 4; ++mt) {
        accA[mt][0] = (f32x4){0.f, 0.f, 0.f, 0.f};
        accA[mt][1] = (f32x4){0.f, 0.f, 0.f, 0.f};
    }
#pragma unroll
    for (int kk = 0; kk < 4; ++kk) {
        bf16x8 av[4];
#pragma unroll
        for (int mt = 0; mt < 4; ++mt)
            av[mt] = *(const bf16x8*)&zb[(mt * 16 + mc) * ZLD + kk * 32 + q * 8];
#pragma unroll
        for (int mt = 0; mt < 4; ++mt) {
            accA[mt][0] = MFMA16(av[mt], pw[kk][0], accA[mt][0]);
            accA[mt][1] = MFMA16(av[mt], pw[kk][1], accA[mt][1]);
            accA[mt][0] = MFMA16(av[mt], pw[kk][2], accA[mt][0]);
            accA[mt][1] = MFMA16(av[mt], pw[kk][3], accA[mt][1]);
        }
    }

    __syncthreads();   // B4a: all z1 reads done -> zC reusable
#pragma unroll
    for (int mt = 0; mt < 4; ++mt)
#pragma unroll
        for (int nj = 0; nj < 2; ++nj)
#pragma unroll
            for (int reg = 0; reg < 4; ++reg)
                zC[(mt * 16 + q * 4 + reg) * 132 + (nn0 + nj) * 16 + mc] = accA[mt][nj][reg];

    // PREFETCH lin2 frags (hot in L2, small; drained at B4).
    bf16x8 pl2[4][2];
#pragma unroll
    for (int kk = 0; kk < 4; ++kk) {
        pl2[kk][0] = LHf[kk * 64 + lane];
        pl2[kk][1] = LLf[kk * 64 + lane];
    }

    __syncthreads();   // B4: lin1 C complete

    // ---- bias + ReLU + LayerNorm 2 on own rows; z2 -> zb own rows ----
    {
        float vv[8][4];
#pragma unroll
        for (int nn = 0; nn < 8; ++nn) {
            float bv = lin1b[nn * 16 + mc];
#pragma unroll
            for (int reg = 0; reg < 4; ++reg)
                vv[nn][reg] = fmaxf(
                    zC[(wid * 16 + q * 4 + reg) * 132 + nn * 16 + mc] + bv, 0.f);
        }
        float mu2[4], rs2[4];
#pragma unroll
        for (int reg = 0; reg < 4; ++reg) {
            float ps = 0.f, pq = 0.f;
#pragma unroll
            for (int nn = 0; nn < 8; ++nn) { float v = vv[nn][reg]; ps += v; pq += v * v; }
#pragma unroll
            for (int o = 1; o <= 8; o <<= 1) { ps += __shfl_xor(ps, o); pq += __shfl_xor(pq, o); }
            float m_ = ps * (1.f / NHID_);
            mu2[reg] = m_;
            rs2[reg] = rsqrtf(pq * (1.f / NHID_) - m_ * m_ + EPS_);
        }
#pragma unroll
        for (int nn = 0; nn < 8; ++nn) {
            int c = nn * 16 + mc;
            float gv = ln2g[c], bv = ln2b[c];
#pragma unroll
            for (int reg = 0; reg < 4; ++reg)
                zb[(wid * 16 + q * 4 + reg) * ZLD + c] =
                    (bf16_t)((vv[nn][reg] - mu2[reg]) * rs2[reg] * gv + bv);
        }
    }
    // z2 rows [wid*16, wid*16+16) written & read by this wave only -> no barrier

    // ---- lin2: own 16 rows, 16x128 @ 128x16(padded); atomic into d_out ----
    f32x4 accO = {0.f, 0.f, 0.f, 0.f};
#pragma unroll
    for (int kk = 0; kk < 4; ++kk) {
        bf16x8 a3 = *(const bf16x8*)&zb[(wid * 16 + mc) * ZLD + kk * 32 + q * 8];
        accO = MFMA16(a3, pl2[kk][0], accO);
        accO = MFMA16(a3, pl2[kk][1], accO);
    }
    if (mc < NCLASS_) {
#pragma unroll
        for (int reg = 0; reg < 4; ++reg)
            atomicAdd(&out[(b0 + q * 4 + reg) * NCLASS_ + mc],
                      accO[reg] * (1.f / NFOREST_));
    }
}

// ---------------------------------------------------------------------------
extern "C" void kernel_launch(void* const* d_in, const int* in_sizes, int n_in,
                              void* d_out, int out_size, void* d_ws, size_t ws_size,
                              hipStream_t stream)
{
    const float* x     = (const float*)d_in[0];
    const float* w1    = (const float*)d_in[1];
    const float* b1    = (const float*)d_in[2];
    const int*   perm  = (const int*)  d_in[3];
    const float* gn1g  = (const float*)d_in[4];
    const float* gn1b  = (const float*)d_in[5];
    const float* w2a   = (const float*)d_in[6];
    const float* b2a   = (const float*)d_in[7];
    const float* gn2g  = (const float*)d_in[8];
    const float* gn2b  = (const float*)d_in[9];
    const float* w2b   = (const float*)d_in[10];
    const float* b2b   = (const float*)d_in[11];
    const float* E     = (const float*)d_in[12];
    const int*   swr   = (const int*)  d_in[13];
    const float* ln1g  = (const float*)d_in[14];
    const float* ln1b  = (const float*)d_in[15];
    const float* lin1w = (const float*)d_in[16];
    const float* lin1b = (const float*)d_in[17];
    const float* ln2g  = (const float*)d_in[18];
    const float* ln2b  = (const float*)d_in[19];
    const float* lin2w = (const float*)d_in[20];
    const float* lin2b = (const float*)d_in[21];

    char* base = (char*)d_ws;
    float*  w_t  = (float*)base;                                    // 4 MB
    float*  x_t  = (float*)(base + 4u * 1024 * 1024 + 64 * 1024);   // 256 KB
    bf16_t* Eh   = (bf16_t*)(base + 4u * 1024 * 1024 + 64 * 1024 + 256 * 1024);
    bf16_t* El   = Eh  + (size_t)EG_FRAGS * 8;
    bf16_t* Wh   = El  + (size_t)EG_FRAGS * 8;
    bf16_t* Wl   = Wh  + (size_t)W1_FRAGS * 8;
    bf16_t* L2h  = Wl  + (size_t)W1_FRAGS * 8;
    bf16_t* L2l  = L2h + (size_t)L2_FRAGS * 8;

    k_xt<<<296, 256, 0, stream>>>(x, lin2b, x_t, (float*)d_out);

    k_main<<<1833, 256, 0, stream>>>(
        E, swr, lin1w, lin2w, x_t, w1, b1, perm, gn1g, gn1b, w2a, b2a,
        gn2g, gn2b, w2b, b2b, Eh, El, Wh, Wl, L2h, L2l, w_t);

    k_forest<<<NFOREST_ * 16, 256, 0, stream>>>(
        w_t, swr, Eh, El, Wh, Wl, L2h, L2l,
        ln1g, ln1b, lin1b, ln2g, ln2b, (float*)d_out);
}